// Round 5
// baseline (698.053 us; speedup 1.0000x reference)
//
#include <hip/hip_runtime.h>
#include <math.h>

#define E_DIM 768
#define S_LEN 1024
#define B_SZ 2
#define H_CNT 12
#define D_HEAD 64
#define M_DIM 768
#define Q_STRIDE 4
#define N_FC1 771            // only M+Q-1 columns of fc1 are consumed
#define LD_H1 772            // padded row stride for h1 (bf16 elements)

typedef __attribute__((ext_vector_type(8))) short bf16x8;
typedef __attribute__((ext_vector_type(4))) float f32x4;

#define AS1 __attribute__((address_space(1)))
#define AS3 __attribute__((address_space(3)))

__device__ __forceinline__ void gld_lds16(void* lds, const void* g) {
    __builtin_amdgcn_global_load_lds((const AS1 void*)g, (AS3 void*)lds, 16, 0, 0);
}

__device__ __forceinline__ short f2bf(float f) {
    unsigned u = __float_as_uint(f);
    unsigned r = (u + 0x7fffu + ((u >> 16) & 1u)) >> 16;
    return (short)r;
}

__device__ __forceinline__ float bf2f(short s) {
    return __uint_as_float(((unsigned)(unsigned short)s) << 16);
}

// ---------------- block reduction helper (256 threads, 4 waves) ------------

__device__ __forceinline__ float block_reduce_sum(float v, volatile float* red) {
#pragma unroll
    for (int off = 32; off > 0; off >>= 1) v += __shfl_xor(v, off);
    __syncthreads();
    if ((threadIdx.x & 63) == 0) red[threadIdx.x >> 6] = v;
    __syncthreads();
    return red[0] + red[1] + red[2] + red[3];
}

// ---------------- weight fp32 -> bf16 conversion ---------------------------

__global__ __launch_bounds__(256) void convert_weights(
        const float* __restrict__ Wq, const float* __restrict__ Wk,
        const float* __restrict__ Wv, const float* __restrict__ Wo,
        const float* __restrict__ fc1W, const float* __restrict__ vqcW,
        const float* __restrict__ fc2W, short* __restrict__ dst) {
    int t = blockIdx.x * 256 + threadIdx.x;       // float4 index
    if (t >= 1475136) return;                     // 5900544 / 4
    int e = t * 4;
    const float* src; int off;
    if      (e < 589824)  { src = Wq;   off = e; }
    else if (e < 1179648) { src = Wk;   off = e - 589824; }
    else if (e < 1769472) { src = Wv;   off = e - 1179648; }
    else if (e < 2359296) { src = Wo;   off = e - 1769472; }
    else if (e < 2951424) { src = fc1W; off = e - 2359296; }
    else if (e < 3541248) { src = vqcW; off = e - 2951424; }
    else                  { src = fc2W; off = e - 3541248; }
    float4 v = *(const float4*)(src + off);
    short4 o = make_short4(f2bf(v.x), f2bf(v.y), f2bf(v.z), f2bf(v.w));
    *(short4*)(dst + e) = o;
}

__global__ void concat_bias(const float* __restrict__ bq, const float* __restrict__ bk,
                            const float* __restrict__ bv, float* __restrict__ bqkv) {
    int i = blockIdx.x * 256 + threadIdx.x;
    if (i >= 2304) return;
    float v = (i < 768) ? bq[i] : (i < 1536) ? bk[i - 768] : bv[i - 1536];
    bqkv[i] = v;
}

// ---------------- LayerNorm: one block per row, E=768, bf16 out ------------

__global__ __launch_bounds__(256) void ln_kernel(const float* __restrict__ x,
                                                 const float* __restrict__ w,
                                                 const float* __restrict__ b,
                                                 short* __restrict__ out) {
    __shared__ float red[4];
    int row = blockIdx.x;
    int tid = threadIdx.x;
    const float* xr = x + (size_t)row * E_DIM;
    float v0 = xr[tid], v1 = xr[tid + 256], v2 = xr[tid + 512];
    float s = block_reduce_sum(v0 + v1 + v2, red);
    float mu = s * (1.0f / E_DIM);
    float d0 = v0 - mu, d1 = v1 - mu, d2 = v2 - mu;
    float var = block_reduce_sum(d0 * d0 + d1 * d1 + d2 * d2, red) * (1.0f / E_DIM);
    float rs = rsqrtf(var + 1e-5f);
    short* orow = out + (size_t)row * E_DIM;
    orow[tid]       = f2bf(d0 * rs * w[tid]       + b[tid]);
    orow[tid + 256] = f2bf(d1 * rs * w[tid + 256] + b[tid + 256]);
    orow[tid + 512] = f2bf(d2 * rs * w[tid + 512] + b[tid + 512]);
}

// ---------------- k row norms from frag-major Kf ---------------------------

__global__ __launch_bounds__(256) void knorm2(const short* __restrict__ Kf,
                                              float* __restrict__ kn) {
    int idx = blockIdx.x * 256 + threadIdx.x;   // bh*1024 + s
    int s = idx & 1023, bh = idx >> 10;
    int jt = s >> 4, ml = s & 15;
    const short* base = Kf + (size_t)(bh * 64 + jt) * 1024 + ml * 8;
    float sum = 0.f;
#pragma unroll
    for (int c = 0; c < 2; c++)
#pragma unroll
        for (int kq = 0; kq < 4; kq++) {
            const short* p = base + c * 512 + kq * 128;
#pragma unroll
            for (int e = 0; e < 8; e++) { float v = bf2f(p[e]); sum += v * v; }
        }
    kn[idx] = sum;
}

// ---------------- bf16 MFMA NT GEMM (double-buffered K-loop) ---------------
// 128x128 tile, BK=32, 256 threads (4 waves 2x2), global_load_lds width 16.
// LDS k-slot XOR swizzle (slot = k ^ ((m>>1)&3)) -> 2-way bank aliasing (free).
// Double-buffered LDS: prefetch tile k+1 issued right after the barrier so
// the barrier's vmcnt drain overlaps the whole MFMA phase (one barrier/iter).
// Split-K via blockIdx.z: block covers K range [z*klen, (z+1)*klen).
// outmode: 0 fp32 row-major; 1 bf16 row-major; 2 bf16 transpose-scatter (vqc);
//          3 QKV split (Q row-major, K/V frag-major); 4 fp32 partial at
//          outp + z*spitch; 5 bf16 partial at outp + z*spitch.

__global__ __launch_bounds__(256) void gemm_bf16(
        const short* __restrict__ A, int lda,
        const short* __restrict__ W, int ldw,
        const float* __restrict__ bias,
        const float* __restrict__ res, int ldr,
        void* __restrict__ outp, int ldo, size_t spitch,
        short* __restrict__ Kfp, short* __restrict__ Vfp,
        int N, int klen, int outmode, int dogelu, int dores) {
    __shared__ short At[2 * 4096];    // 2 buffers x 128x32
    __shared__ short Bt[2 * 4096];
    const int tid = threadIdx.x;
    const int lane = tid & 63;
    const int wave = tid >> 6;
    const int wr = (wave >> 1) * 64;
    const int wc = (wave & 1) * 64;
    const int ml = lane & 15;
    const int kq = lane >> 4;
    const int row0 = blockIdx.y * 128;
    const int col0 = blockIdx.x * 128;
    const int kbase = blockIdx.z * klen;

    // staging: chunk c -> LDS shorts [c*8, c*8+8); logical (m=c>>2,
    // kslot=c&3); source k-chunk = kslot ^ ((m>>1)&3)  (XOR swizzle)
    const int c0 = tid, c1 = tid + 256;
    const int am0 = c0 >> 2, ak0 = (((c0 & 3) ^ ((am0 >> 1) & 3))) * 8;
    const int am1 = c1 >> 2, ak1 = (((c1 & 3) ^ ((am1 >> 1) & 3))) * 8;
    const short* Ag0 = A + (size_t)(row0 + am0) * lda + ak0 + kbase;
    const short* Ag1 = A + (size_t)(row0 + am1) * lda + ak1 + kbase;
    int wrow0 = col0 + am0; if (wrow0 > N - 1) wrow0 = N - 1;
    int wrow1 = col0 + am1; if (wrow1 > N - 1) wrow1 = N - 1;
    const short* Wg0 = W + (size_t)wrow0 * ldw + ak0 + kbase;
    const short* Wg1 = W + (size_t)wrow1 * ldw + ak1 + kbase;

    const int kxor = (kq ^ ((ml >> 1) & 3)) * 8;   // reader swizzle

    f32x4 zero = {0.f, 0.f, 0.f, 0.f};
    f32x4 acc[4][4];
#pragma unroll
    for (int i = 0; i < 4; i++)
#pragma unroll
        for (int j = 0; j < 4; j++) acc[i][j] = zero;

    // prologue: tile 0 into buffer 0
    gld_lds16(At + c0 * 8, Ag0);
    gld_lds16(At + c1 * 8, Ag1);
    gld_lds16(Bt + c0 * 8, Wg0);
    gld_lds16(Bt + c1 * 8, Wg1);

    int o = 0;
    for (int k0 = 0; k0 < klen; k0 += 32) {
        __syncthreads();            // tile k0 resident; prior reads of buf^1 done
        int no = o ^ 4096;
        if (k0 + 32 < klen) {       // prefetch next tile (in flight during MFMA)
            int nk = k0 + 32;
            gld_lds16(At + no + c0 * 8, Ag0 + nk);
            gld_lds16(At + no + c1 * 8, Ag1 + nk);
            gld_lds16(Bt + no + c0 * 8, Wg0 + nk);
            gld_lds16(Bt + no + c1 * 8, Wg1 + nk);
        }
        bf16x8 af[4], bfr[4];
#pragma unroll
        for (int i = 0; i < 4; i++)
            af[i] = *(const bf16x8*)&At[o + (wr + i * 16 + ml) * 32 + kxor];
#pragma unroll
        for (int j = 0; j < 4; j++)
            bfr[j] = *(const bf16x8*)&Bt[o + (wc + j * 16 + ml) * 32 + kxor];
#pragma unroll
        for (int i = 0; i < 4; i++)
#pragma unroll
            for (int j = 0; j < 4; j++)
                acc[i][j] = __builtin_amdgcn_mfma_f32_16x16x32_bf16(af[i], bfr[j], acc[i][j], 0, 0, 0);
        o = no;
    }

    // epilogue: C/D layout col = lane&15, row = (lane>>4)*4 + reg
#pragma unroll
    for (int i = 0; i < 4; i++) {
#pragma unroll
        for (int j = 0; j < 4; j++) {
#pragma unroll
            for (int rr = 0; rr < 4; rr++) {
                int r = row0 + wr + i * 16 + kq * 4 + rr;
                int c = col0 + wc + j * 16 + ml;
                if (c < N) {
                    float v = acc[i][j][rr];
                    if (outmode < 4) v += bias[c];
                    if (dores) v += res[(size_t)r * ldr + c];
                    if (dogelu) v = 0.5f * v * (1.0f + erff(v * 0.70710678118654752f));
                    if (outmode == 0)      ((float*)outp)[(size_t)r * ldo + c] = v;
                    else if (outmode == 1) ((short*)outp)[(size_t)r * ldo + c] = f2bf(v);
                    else if (outmode == 2) ((short*)outp)[(size_t)(r >> 2) * ldo + c * 4 + (r & 3)] = f2bf(v);
                    else if (outmode == 4) ((float*)outp)[blockIdx.z * spitch + (size_t)r * ldo + c] = v;
                    else if (outmode == 5) ((short*)outp)[blockIdx.z * spitch + (size_t)r * ldo + c] = f2bf(v);
                    else {
                        int s = r & 1023, bb = r >> 10;
                        if (c < 768) {
                            ((short*)outp)[(size_t)r * 768 + c] = f2bf(v);
                        } else if (c < 1536) {
                            int df = c - 768; int hh = df >> 6, d = df & 63;
                            int bh2 = bb * 12 + hh;
                            size_t idx = ((size_t)(bh2 * 64 + (s >> 4)) * 2 + (d >> 5)) * 512
                                       + (size_t)((d >> 3) & 3) * 128 + (size_t)(s & 15) * 8 + (d & 7);
                            Kfp[idx] = f2bf(v);
                        } else {
                            int df = c - 1536; int hh = df >> 6, d = df & 63;
                            int bh2 = bb * 12 + hh;
                            size_t idx = ((size_t)(bh2 * 32 + (s >> 5))) * 2048
                                       + (size_t)(d >> 4) * 512 + (size_t)((s >> 3) & 3) * 128
                                       + (size_t)(d & 15) * 8 + (s & 7);
                            Vfp[idx] = f2bf(v);
                        }
                    }
                }
            }
        }
    }
}

// ---------------- split-K reduce kernels -----------------------------------

// Wo partials (4, fp32) + bo + residual x -> x2 fp32, then LN(ln2) -> y bf16
__global__ __launch_bounds__(256) void reduce_wo_ln(
        const float* __restrict__ part, const float* __restrict__ bo,
        const float* __restrict__ x, const float* __restrict__ w,
        const float* __restrict__ bvec, float* __restrict__ x2,
        short* __restrict__ y) {
    __shared__ float red[4];
    int row = blockIdx.x, tid = threadIdx.x;
    const size_t SP = (size_t)2048 * 768;
    const float* pr = part + (size_t)row * 768;
    const float* xr = x + (size_t)row * 768;
    float* x2r = x2 + (size_t)row * 768;
    float v[3];
#pragma unroll
    for (int u = 0; u < 3; u++) {
        int c = tid + u * 256;
        float s = bo[c] + xr[c];
#pragma unroll
        for (int z = 0; z < 4; z++) s += pr[z * SP + c];
        v[u] = s; x2r[c] = s;
    }
    float s = block_reduce_sum(v[0] + v[1] + v[2], red);
    float mu = s * (1.0f / 768.f);
    float d0 = v[0] - mu, d1 = v[1] - mu, d2 = v[2] - mu;
    float var = block_reduce_sum(d0 * d0 + d1 * d1 + d2 * d2, red) * (1.0f / 768.f);
    float rs = rsqrtf(var + 1e-5f);
    short* orow = y + (size_t)row * 768;
    orow[tid]       = f2bf(d0 * rs * w[tid]       + bvec[tid]);
    orow[tid + 256] = f2bf(d1 * rs * w[tid + 256] + bvec[tid + 256]);
    orow[tid + 512] = f2bf(d2 * rs * w[tid + 512] + bvec[tid + 512]);
}

// fc1 partials (4, fp32) + bias -> h1 bf16 [2048][772], cols 0..770
__global__ __launch_bounds__(256) void reduce_fc1(
        const float* __restrict__ part, const float* __restrict__ b,
        short* __restrict__ h1) {
    int row = blockIdx.x, tid = threadIdx.x;
    const size_t SP = (size_t)2048 * LD_H1;
    const float* pr = part + (size_t)row * LD_H1;
    short* o = h1 + (size_t)row * LD_H1;
#pragma unroll
    for (int u = 0; u < 3; u++) {
        int c = tid + u * 256;
        float s = b[c];
#pragma unroll
        for (int z = 0; z < 4; z++) s += pr[z * SP + c];
        o[c] = f2bf(s);
    }
    if (tid < 3) {
        int c = 768 + tid;
        float s = b[c];
#pragma unroll
        for (int z = 0; z < 4; z++) s += pr[z * SP + c];
        o[c] = f2bf(s);
    }
}

// fc2 partials (8, bf16) + bias + residual x2 -> out fp32
__global__ __launch_bounds__(256) void reduce_fc2(
        const short* __restrict__ part, const float* __restrict__ b,
        const float* __restrict__ x2, float* __restrict__ out) {
    int t = blockIdx.x * 256 + threadIdx.x;     // 4-elem group; 393216 total
    int row = t / 192;
    int c = (t - row * 192) * 4;
    size_t off = (size_t)row * 768 + c;
    const size_t SP = (size_t)2048 * 768;
    float4 bb = *(const float4*)(b + c);
    float4 xx = *(const float4*)(x2 + off);
    float o0 = bb.x + xx.x, o1 = bb.y + xx.y, o2 = bb.z + xx.z, o3 = bb.w + xx.w;
#pragma unroll
    for (int z = 0; z < 8; z++) {
        short4 v = *(const short4*)(part + z * SP + off);
        o0 += bf2f(v.x); o1 += bf2f(v.y); o2 += bf2f(v.z); o3 += bf2f(v.w);
    }
    float4 o = make_float4(o0, o1, o2, o3);
    *(float4*)(out + off) = o;
}

// ---------------- expand h1 [2048][772] -> Avqc [8192][768] (bf16) ---------

__global__ __launch_bounds__(256) void expand_kernel(const short* __restrict__ h1,
                                                     short* __restrict__ out) {
    int t = blockIdx.x * 256 + threadIdx.x;
    int r = t / 192;
    int c4 = (t - r * 192) * 4;
    const short* s = h1 + (size_t)(r >> 2) * LD_H1 + (r & 3) + c4;
    short4 v = make_short4(s[0], s[1], s[2], s[3]);
    *(short4*)(out + (size_t)r * M_DIM + c4) = v;
}

// ---------------- MFMA fused attention (double-buffered K/V tiles) ---------

__global__ __launch_bounds__(256) void attn_mfma(
        const short* __restrict__ Qb,    // [2048][768] bf16
        const short* __restrict__ Kf,    // frag-major
        const short* __restrict__ Vf,    // frag-major
        const float* __restrict__ kn,    // [24][1024]
        const float* __restrict__ pond,
        short* __restrict__ vals) {      // [2048][768] bf16
    __shared__ __align__(16) short Kt[2 * 4096];
    __shared__ __align__(16) short Vt[2 * 4096];
    __shared__ float knl[1024];
    __shared__ float qn_l[4][16];
    __shared__ float is_l[4][16];
    __shared__ __align__(16) short Pe[4 * 16 * 72];
    __shared__ __align__(16) short Pr[4 * 16 * 72];

    const int tid = threadIdx.x;
    const int lane = tid & 63;
    const int wave = tid >> 6;
    const int ml = lane & 15;
    const int kq = lane >> 4;
    const int qt = blockIdx.x, h = blockIdx.y, b = blockIdx.z;
    const int bh = b * H_CNT + h;

    const short* KfB = Kf + (size_t)bh * 65536;
    const short* VfB = Vf + (size_t)bh * 65536;

    // prologue: tile 0 into buffer 0
    {
        const short* sk = KfB + tid * 8;
        gld_lds16(Kt + tid * 8, sk);
        gld_lds16(Kt + 2048 + tid * 8, sk + 2048);
        const short* sv = VfB + tid * 8;
        gld_lds16(Vt + tid * 8, sv);
        gld_lds16(Vt + 2048 + tid * 8, sv + 2048);
    }

    for (int i = tid; i < 1024; i += 256) knl[i] = kn[bh * 1024 + i];

    const int qrow = b * S_LEN + qt * 64 + wave * 16 + ml;
    const short* qp = Qb + (size_t)qrow * 768 + h * 64 + kq * 8;
    bf16x8 aq0 = *(const bf16x8*)qp;
    bf16x8 aq1 = *(const bf16x8*)(qp + 32);

    float qn_part = 0.f;
#pragma unroll
    for (int e = 0; e < 8; e++) {
        float v0 = bf2f(aq0[e]), v1 = bf2f(aq1[e]);
        qn_part += v0 * v0 + v1 * v1;
    }
    qn_part += __shfl_xor(qn_part, 16);
    qn_part += __shfl_xor(qn_part, 32);
    if (kq == 0) {
        qn_l[wave][ml] = qn_part;
        float sig = fminf(fmaxf(qn_part, 1e-8f), 1e4f);
        is_l[wave][ml] = 1.0f / sig;
    }
    __syncthreads();

    float qn_r[4], is_r[4];
#pragma unroll
    for (int r = 0; r < 4; r++) {
        qn_r[r] = qn_l[wave][kq * 4 + r];
        is_r[r] = is_l[wave][kq * 4 + r];
    }

    f32x4 Oe[4], Or[4];
#pragma unroll
    for (int dt = 0; dt < 4; dt++) { Oe[dt] = {0.f,0.f,0.f,0.f}; Or[dt] = {0.f,0.f,0.f,0.f}; }
    float es_p[4] = {0.f,0.f,0.f,0.f}, rs_p[4] = {0.f,0.f,0.f,0.f};

    short* PeW = Pe + wave * 1152;
    short* PrW = Pr + wave * 1152;

    int o = 0;
    for (int t = 0; t < 16; t++) {
        __syncthreads();   // tile t resident (vmcnt drain); P-buf free
        int no = o ^ 4096;
        if (t < 15) {      // prefetch tile t+1 (hidden under QK+exp phase)
            const short* sk = KfB + (t + 1) * 4096 + tid * 8;
            gld_lds16(Kt + no + tid * 8, sk);
            gld_lds16(Kt + no + 2048 + tid * 8, sk + 2048);
            const short* sv = VfB + (t + 1) * 4096 + tid * 8;
            gld_lds16(Vt + no + tid * 8, sv);
            gld_lds16(Vt + no + 2048 + tid * 8, sv + 2048);
        }

#pragma unroll
        for (int jtl = 0; jtl < 4; jtl++) {
            bf16x8 bk0 = *(const bf16x8*)&Kt[o + (jtl * 2 + 0) * 512 + lane * 8];
            bf16x8 bk1 = *(const bf16x8*)&Kt[o + (jtl * 2 + 1) * 512 + lane * 8];
            f32x4 c = {0.f,0.f,0.f,0.f};
            c = __builtin_amdgcn_mfma_f32_16x16x32_bf16(aq0, bk0, c, 0, 0, 0);
            c = __builtin_amdgcn_mfma_f32_16x16x32_bf16(aq1, bk1, c, 0, 0, 0);
            float knj = knl[t * 64 + jtl * 16 + ml];
#pragma unroll
            for (int r = 0; r < 4; r++) {
                float qk = c[r];
                float e = __expf(qk * 0.125f);
                float tt = (2.f * qk - qn_r[r] - knj) * is_r[r];
                float rb = fminf(__expf(tt), 1.0f);
                es_p[r] += e; rs_p[r] += rb;
                PeW[(kq * 4 + r) * 72 + jtl * 16 + ml] = f2bf(e);
                PrW[(kq * 4 + r) * 72 + jtl * 16 + ml] = f2bf(rb);
            }
        }
        __syncthreads();   // P visible

#pragma unroll
        for (int jcl = 0; jcl < 2; jcl++) {
            bf16x8 pa_e = *(const bf16x8*)&PeW[ml * 72 + jcl * 32 + kq * 8];
            bf16x8 pa_r = *(const bf16x8*)&PrW[ml * 72 + jcl * 32 + kq * 8];
#pragma unroll
            for (int dt = 0; dt < 4; dt++) {
                bf16x8 bv = *(const bf16x8*)&Vt[o + (jcl * 4 + dt) * 512 + lane * 8];
                Oe[dt] = __builtin_amdgcn_mfma_f32_16x16x32_bf16(pa_e, bv, Oe[dt], 0, 0, 0);
                Or[dt] = __builtin_amdgcn_mfma_f32_16x16x32_bf16(pa_r, bv, Or[dt], 0, 0, 0);
            }
        }
        o = no;
    }

#pragma unroll
    for (int off = 1; off <= 8; off <<= 1) {
#pragma unroll
        for (int r = 0; r < 4; r++) {
            es_p[r] += __shfl_xor(es_p[r], off);
            rs_p[r] += __shfl_xor(rs_p[r], off);
        }
    }

    float p = pond[0];
    float sv = 1.0f / (1.0f + __expf(-p));
    float p0 = 1.0f - sv, p1 = sv;
    float blendinv = 1.0f / (p0 + p1 + 1e-7f);
    float we[4], wr[4];
#pragma unroll
    for (int r = 0; r < 4; r++) {
        we[r] = p0 * blendinv / es_p[r];
        wr[r] = p1 * blendinv / fmaxf(rs_p[r], 1e-8f);
    }

#pragma unroll
    for (int dt = 0; dt < 4; dt++) {
#pragma unroll
        for (int r = 0; r < 4; r++) {
            float v = Oe[dt][r] * we[r] + Or[dt][r] * wr[r];
            int token = b * S_LEN + qt * 64 + wave * 16 + kq * 4 + r;
            vals[(size_t)token * 768 + h * 64 + dt * 16 + ml] = f2bf(v);
        }
    }
}

// ---------------- launcher -------------------------------------------------

extern "C" void kernel_launch(void* const* d_in, const int* in_sizes, int n_in,
                              void* d_out, int out_size, void* d_ws, size_t ws_size,
                              hipStream_t stream) {
    const float* x     = (const float*)d_in[0];
    const float* ln1_w = (const float*)d_in[1];
    const float* ln1_b = (const float*)d_in[2];
    const float* Wq    = (const float*)d_in[3];
    const float* bq    = (const float*)d_in[4];
    const float* Wk    = (const float*)d_in[5];
    const float* bk    = (const float*)d_in[6];
    const float* Wv    = (const float*)d_in[7];
    const float* bv    = (const float*)d_in[8];
    const float* Wo    = (const float*)d_in[9];
    const float* bo    = (const float*)d_in[10];
    const float* pond  = (const float*)d_in[11];
    const float* ln2_w = (const float*)d_in[12];
    const float* ln2_b = (const float*)d_in[13];
    const float* fc1_W = (const float*)d_in[14];
    const float* fc1_b = (const float*)d_in[15];
    const float* vqc_W = (const float*)d_in[16];
    const float* vqc_b = (const float*)d_in[17];
    const float* fc2_W = (const float*)d_in[18];
    const float* fc2_b = (const float*)d_in[19];
    float* out = (float*)d_out;

    char* p = (char*)d_ws;
    short* Qb   = (short*)p;  p += (size_t)2048 * 768 * 2;
    short* Kfb  = (short*)p;  p += (size_t)2048 * 768 * 2;
    short* Vfb  = (short*)p;  p += (size_t)2048 * 768 * 2;
    float* x2   = (float*)p;  p += (size_t)2048 * 768 * 4;
    float* kn   = (float*)p;  p += (size_t)24576 * 4;
    float* bqkv = (float*)p;  p += 2304 * 4;
    short* actb = (short*)p;  p += (size_t)2048 * 768 * 2;
    short* h1   = (short*)p;  p += (size_t)2048 * LD_H1 * 2;
    short* g    = (short*)p;  p += (size_t)2048 * 3072 * 2;
    short* Avqc = (short*)p;  p += (size_t)8192 * 768 * 2;
    float* partb = (float*)p; p += (size_t)4 * 2048 * LD_H1 * 4;   // split-K partials (25.3 MB)
    short* wreg = (short*)p;  p += (size_t)5900544 * 2;
    short* Wqkvb = wreg;
    short* Wob   = wreg + 1769472;
    short* fc1b  = wreg + 2359296;
    short* vqcb  = wreg + 2951424;
    short* fc2b  = wreg + 3541248;

    dim3 blk(256);
    const size_t SP768 = (size_t)2048 * 768;
    const size_t SP772 = (size_t)2048 * LD_H1;

    convert_weights<<<5763, blk, 0, stream>>>(Wq, Wk, Wv, Wo, fc1_W, vqc_W, fc2_W, wreg);
    concat_bias<<<9, blk, 0, stream>>>(bq, bk, bv, bqkv);

    // 1. ln1 -> actb (bf16)
    ln_kernel<<<2048, blk, 0, stream>>>(x, ln1_w, ln1_b, actb);
    // 2. fused QKV projection -> Qb row-major, Kf/Vf frag-major (all bf16)
    gemm_bf16<<<dim3(18, 16, 1), blk, 0, stream>>>(actb, 768, Wqkvb, 768, bqkv, nullptr, 0,
                                                   Qb, 768, 0, Kfb, Vfb, 2304, 768, 3, 0, 0);
    // 3. k norms from Kf
    knorm2<<<96, blk, 0, stream>>>(Kfb, kn);
    // 4. MFMA attention -> vals (actb, bf16)
    attn_mfma<<<dim3(16, 12, 2), blk, 0, stream>>>(Qb, Kfb, Vfb, kn, pond, actb);
    // 5. Wo split-K x4 -> fp32 partials
    gemm_bf16<<<dim3(6, 16, 4), blk, 0, stream>>>(actb, 768, Wob, 768, bo, nullptr, 0,
                                                  partb, 768, SP768, nullptr, nullptr,
                                                  768, 192, 4, 0, 0);
    // 6. reduce + bo + residual(x) -> x2 fp32, fused ln2 -> actb
    reduce_wo_ln<<<2048, blk, 0, stream>>>(partb, bo, x, ln2_w, ln2_b, x2, actb);
    // 7. fc1 split-K x4 (N=771) -> fp32 partials [2048][772]
    gemm_bf16<<<dim3(7, 16, 4), blk, 0, stream>>>(actb, 768, fc1b, 768, fc1_b, nullptr, 0,
                                                  partb, LD_H1, SP772, nullptr, nullptr,
                                                  N_FC1, 192, 4, 0, 0);
    // 8. reduce + bias -> h1 bf16
    reduce_fc1<<<2048, blk, 0, stream>>>(partb, fc1_b, h1);
    // 9. expand slices -> Avqc [8192][768]
    expand_kernel<<<6144, blk, 0, stream>>>(h1, Avqc);
    // 10. vqc + gelu + transpose scatter -> g bf16 [2048][3072]
    gemm_bf16<<<dim3(6, 64, 1), blk, 0, stream>>>(Avqc, 768, vqcb, 768, vqc_b, nullptr, 0,
                                                  g, 3072, 0, nullptr, nullptr, 768, 768, 2, 1, 0);
    // 11. fc2 split-K x8 -> bf16 partials (fits the same 25 MB buffer)
    gemm_bf16<<<dim3(6, 16, 8), blk, 0, stream>>>(g, 3072, fc2b, 3072, fc2_b, nullptr, 0,
                                                  partb, 768, SP768, nullptr, nullptr,
                                                  768, 384, 5, 0, 0);
    // 12. reduce + bias + residual(x2) -> out fp32
    reduce_fc2<<<1536, blk, 0, stream>>>((const short*)partb, fc2_b, x2, out);
}

// Round 6
// 697.074 us; speedup vs baseline: 1.0014x; 1.0014x over previous
//
#include <hip/hip_runtime.h>
#include <math.h>

#define E_DIM 768
#define S_LEN 1024
#define B_SZ 2
#define H_CNT 12
#define D_HEAD 64
#define M_DIM 768
#define Q_STRIDE 4
#define N_FC1 771            // only M+Q-1 columns of fc1 are consumed
#define LD_H1 772            // padded row stride for h1 (bf16 elements)

typedef __attribute__((ext_vector_type(8))) short bf16x8;
typedef __attribute__((ext_vector_type(4))) float f32x4;

#define AS1 __attribute__((address_space(1)))
#define AS3 __attribute__((address_space(3)))

__device__ __forceinline__ void gld_lds16(void* lds, const void* g) {
    __builtin_amdgcn_global_load_lds((const AS1 void*)g, (AS3 void*)lds, 16, 0, 0);
}

__device__ __forceinline__ short f2bf(float f) {
    unsigned u = __float_as_uint(f);
    unsigned r = (u + 0x7fffu + ((u >> 16) & 1u)) >> 16;
    return (short)r;
}

__device__ __forceinline__ float bf2f(short s) {
    return __uint_as_float(((unsigned)(unsigned short)s) << 16);
}

// ---------------- block reduction helper (256 threads, 4 waves) ------------

__device__ __forceinline__ float block_reduce_sum(float v, volatile float* red) {
#pragma unroll
    for (int off = 32; off > 0; off >>= 1) v += __shfl_xor(v, off);
    __syncthreads();
    if ((threadIdx.x & 63) == 0) red[threadIdx.x >> 6] = v;
    __syncthreads();
    return red[0] + red[1] + red[2] + red[3];
}

// ---------------- weight fp32 -> bf16 conversion ---------------------------

__global__ __launch_bounds__(256) void convert_weights(
        const float* __restrict__ Wq, const float* __restrict__ Wk,
        const float* __restrict__ Wv, const float* __restrict__ Wo,
        const float* __restrict__ fc1W, const float* __restrict__ vqcW,
        const float* __restrict__ fc2W, short* __restrict__ dst) {
    int t = blockIdx.x * 256 + threadIdx.x;       // float4 index
    if (t >= 1475136) return;                     // 5900544 / 4
    int e = t * 4;
    const float* src; int off;
    if      (e < 589824)  { src = Wq;   off = e; }
    else if (e < 1179648) { src = Wk;   off = e - 589824; }
    else if (e < 1769472) { src = Wv;   off = e - 1179648; }
    else if (e < 2359296) { src = Wo;   off = e - 1769472; }
    else if (e < 2951424) { src = fc1W; off = e - 2359296; }
    else if (e < 3541248) { src = vqcW; off = e - 2951424; }
    else                  { src = fc2W; off = e - 3541248; }
    float4 v = *(const float4*)(src + off);
    short4 o = make_short4(f2bf(v.x), f2bf(v.y), f2bf(v.z), f2bf(v.w));
    *(short4*)(dst + e) = o;
}

__global__ void concat_bias(const float* __restrict__ bq, const float* __restrict__ bk,
                            const float* __restrict__ bv, float* __restrict__ bqkv) {
    int i = blockIdx.x * 256 + threadIdx.x;
    if (i >= 2304) return;
    float v = (i < 768) ? bq[i] : (i < 1536) ? bk[i - 768] : bv[i - 1536];
    bqkv[i] = v;
}

// ---------------- LayerNorm: one block per row, E=768, bf16 out ------------

__global__ __launch_bounds__(256) void ln_kernel(const float* __restrict__ x,
                                                 const float* __restrict__ w,
                                                 const float* __restrict__ b,
                                                 short* __restrict__ out) {
    __shared__ float red[4];
    int row = blockIdx.x;
    int tid = threadIdx.x;
    const float* xr = x + (size_t)row * E_DIM;
    float v0 = xr[tid], v1 = xr[tid + 256], v2 = xr[tid + 512];
    float s = block_reduce_sum(v0 + v1 + v2, red);
    float mu = s * (1.0f / E_DIM);
    float d0 = v0 - mu, d1 = v1 - mu, d2 = v2 - mu;
    float var = block_reduce_sum(d0 * d0 + d1 * d1 + d2 * d2, red) * (1.0f / E_DIM);
    float rs = rsqrtf(var + 1e-5f);
    short* orow = out + (size_t)row * E_DIM;
    orow[tid]       = f2bf(d0 * rs * w[tid]       + b[tid]);
    orow[tid + 256] = f2bf(d1 * rs * w[tid + 256] + b[tid + 256]);
    orow[tid + 512] = f2bf(d2 * rs * w[tid + 512] + b[tid + 512]);
}

// ---------------- k row norms from frag-major Kf ---------------------------

__global__ __launch_bounds__(256) void knorm2(const short* __restrict__ Kf,
                                              float* __restrict__ kn) {
    int idx = blockIdx.x * 256 + threadIdx.x;   // bh*1024 + s
    int s = idx & 1023, bh = idx >> 10;
    int jt = s >> 4, ml = s & 15;
    const short* base = Kf + (size_t)(bh * 64 + jt) * 1024 + ml * 8;
    float sum = 0.f;
#pragma unroll
    for (int c = 0; c < 2; c++)
#pragma unroll
        for (int kq = 0; kq < 4; kq++) {
            const short* p = base + c * 512 + kq * 128;
#pragma unroll
            for (int e = 0; e < 8; e++) { float v = bf2f(p[e]); sum += v * v; }
        }
    kn[idx] = sum;
}

// ---------------- bf16 MFMA NT GEMM (single-buffer, R4-proven) -------------
// 128x128 tile, BK=32, 256 threads (4 waves 2x2), global_load_lds width 16.
// LDS k-slot XOR swizzle (slot = k ^ ((m>>1)&3)) -> 2-way bank aliasing (free).
// Split-K via blockIdx.z: block covers K range [z*klen, (z+1)*klen).
// NOTE: double-buffering this loop (R5) triggered accumulator spills to
// scratch (VGPR 88->68, WRITE_SIZE 9MB->450MB) — keep single-buffer.
// outmode: 0 fp32 row-major; 1 bf16 row-major; 2 bf16 transpose-scatter (vqc);
//          3 QKV split (Q row-major, K/V frag-major); 4 fp32 partial at
//          outp + z*spitch; 5 bf16 partial at outp + z*spitch.

__global__ __launch_bounds__(256) void gemm_bf16(
        const short* __restrict__ A, int lda,
        const short* __restrict__ W, int ldw,
        const float* __restrict__ bias,
        const float* __restrict__ res, int ldr,
        void* __restrict__ outp, int ldo, size_t spitch,
        short* __restrict__ Kfp, short* __restrict__ Vfp,
        int N, int klen, int outmode, int dogelu, int dores) {
    __shared__ short At[128 * 32];
    __shared__ short Bt[128 * 32];
    const int tid = threadIdx.x;
    const int lane = tid & 63;
    const int wave = tid >> 6;
    const int wr = (wave >> 1) * 64;
    const int wc = (wave & 1) * 64;
    const int ml = lane & 15;
    const int kq = lane >> 4;
    const int row0 = blockIdx.y * 128;
    const int col0 = blockIdx.x * 128;
    const int kbase = blockIdx.z * klen;

    // staging: chunk c -> LDS shorts [c*8, c*8+8); logical (m=c>>2,
    // kslot=c&3); source k-chunk = kslot ^ ((m>>1)&3)  (XOR swizzle)
    const int c0 = tid, c1 = tid + 256;
    const int am0 = c0 >> 2, ak0 = (((c0 & 3) ^ ((am0 >> 1) & 3))) * 8;
    const int am1 = c1 >> 2, ak1 = (((c1 & 3) ^ ((am1 >> 1) & 3))) * 8;
    const short* Ag0 = A + (size_t)(row0 + am0) * lda + ak0 + kbase;
    const short* Ag1 = A + (size_t)(row0 + am1) * lda + ak1 + kbase;
    int wrow0 = col0 + am0; if (wrow0 > N - 1) wrow0 = N - 1;
    int wrow1 = col0 + am1; if (wrow1 > N - 1) wrow1 = N - 1;
    const short* Wg0 = W + (size_t)wrow0 * ldw + ak0 + kbase;
    const short* Wg1 = W + (size_t)wrow1 * ldw + ak1 + kbase;

    const int kxor = (kq ^ ((ml >> 1) & 3)) * 8;   // reader swizzle

    f32x4 zero = {0.f, 0.f, 0.f, 0.f};
    f32x4 acc[4][4];
#pragma unroll
    for (int i = 0; i < 4; i++)
#pragma unroll
        for (int j = 0; j < 4; j++) acc[i][j] = zero;

    for (int k0 = 0; k0 < klen; k0 += 32) {
        gld_lds16(At + c0 * 8, Ag0 + k0);
        gld_lds16(At + c1 * 8, Ag1 + k0);
        gld_lds16(Bt + c0 * 8, Wg0 + k0);
        gld_lds16(Bt + c1 * 8, Wg1 + k0);
        __syncthreads();
        bf16x8 af[4], bfr[4];
#pragma unroll
        for (int i = 0; i < 4; i++)
            af[i] = *(const bf16x8*)&At[(wr + i * 16 + ml) * 32 + kxor];
#pragma unroll
        for (int j = 0; j < 4; j++)
            bfr[j] = *(const bf16x8*)&Bt[(wc + j * 16 + ml) * 32 + kxor];
#pragma unroll
        for (int i = 0; i < 4; i++)
#pragma unroll
            for (int j = 0; j < 4; j++)
                acc[i][j] = __builtin_amdgcn_mfma_f32_16x16x32_bf16(af[i], bfr[j], acc[i][j], 0, 0, 0);
        __syncthreads();
    }

    // epilogue: C/D layout col = lane&15, row = (lane>>4)*4 + reg
#pragma unroll
    for (int i = 0; i < 4; i++) {
#pragma unroll
        for (int j = 0; j < 4; j++) {
#pragma unroll
            for (int rr = 0; rr < 4; rr++) {
                int r = row0 + wr + i * 16 + kq * 4 + rr;
                int c = col0 + wc + j * 16 + ml;
                if (c < N) {
                    float v = acc[i][j][rr];
                    if (outmode < 4) v += bias[c];
                    if (dores) v += res[(size_t)r * ldr + c];
                    if (dogelu) v = 0.5f * v * (1.0f + erff(v * 0.70710678118654752f));
                    if (outmode == 0)      ((float*)outp)[(size_t)r * ldo + c] = v;
                    else if (outmode == 1) ((short*)outp)[(size_t)r * ldo + c] = f2bf(v);
                    else if (outmode == 2) ((short*)outp)[(size_t)(r >> 2) * ldo + c * 4 + (r & 3)] = f2bf(v);
                    else if (outmode == 4) ((float*)outp)[blockIdx.z * spitch + (size_t)r * ldo + c] = v;
                    else if (outmode == 5) ((short*)outp)[blockIdx.z * spitch + (size_t)r * ldo + c] = f2bf(v);
                    else {
                        int s = r & 1023, bb = r >> 10;
                        if (c < 768) {
                            ((short*)outp)[(size_t)r * 768 + c] = f2bf(v);
                        } else if (c < 1536) {
                            int df = c - 768; int hh = df >> 6, d = df & 63;
                            int bh2 = bb * 12 + hh;
                            size_t idx = ((size_t)(bh2 * 64 + (s >> 4)) * 2 + (d >> 5)) * 512
                                       + (size_t)((d >> 3) & 3) * 128 + (size_t)(s & 15) * 8 + (d & 7);
                            Kfp[idx] = f2bf(v);
                        } else {
                            int df = c - 1536; int hh = df >> 6, d = df & 63;
                            int bh2 = bb * 12 + hh;
                            size_t idx = ((size_t)(bh2 * 32 + (s >> 5))) * 2048
                                       + (size_t)(d >> 4) * 512 + (size_t)((s >> 3) & 3) * 128
                                       + (size_t)(d & 15) * 8 + (s & 7);
                            Vfp[idx] = f2bf(v);
                        }
                    }
                }
            }
        }
    }
}

// ---------------- split-K reduce kernels -----------------------------------

// Wo partials (4, fp32) + bo + residual x -> x2 fp32, then LN(ln2) -> y bf16
__global__ __launch_bounds__(256) void reduce_wo_ln(
        const float* __restrict__ part, const float* __restrict__ bo,
        const float* __restrict__ x, const float* __restrict__ w,
        const float* __restrict__ bvec, float* __restrict__ x2,
        short* __restrict__ y) {
    __shared__ float red[4];
    int row = blockIdx.x, tid = threadIdx.x;
    const size_t SP = (size_t)2048 * 768;
    const float* pr = part + (size_t)row * 768;
    const float* xr = x + (size_t)row * 768;
    float* x2r = x2 + (size_t)row * 768;
    float v[3];
#pragma unroll
    for (int u = 0; u < 3; u++) {
        int c = tid + u * 256;
        float s = bo[c] + xr[c];
#pragma unroll
        for (int z = 0; z < 4; z++) s += pr[z * SP + c];
        v[u] = s; x2r[c] = s;
    }
    float s = block_reduce_sum(v[0] + v[1] + v[2], red);
    float mu = s * (1.0f / 768.f);
    float d0 = v[0] - mu, d1 = v[1] - mu, d2 = v[2] - mu;
    float var = block_reduce_sum(d0 * d0 + d1 * d1 + d2 * d2, red) * (1.0f / 768.f);
    float rs = rsqrtf(var + 1e-5f);
    short* orow = y + (size_t)row * 768;
    orow[tid]       = f2bf(d0 * rs * w[tid]       + bvec[tid]);
    orow[tid + 256] = f2bf(d1 * rs * w[tid + 256] + bvec[tid + 256]);
    orow[tid + 512] = f2bf(d2 * rs * w[tid + 512] + bvec[tid + 512]);
}

// fc1 partials (4, fp32) + bias -> h1 bf16 [2048][772], cols 0..770
__global__ __launch_bounds__(256) void reduce_fc1(
        const float* __restrict__ part, const float* __restrict__ b,
        short* __restrict__ h1) {
    int row = blockIdx.x, tid = threadIdx.x;
    const size_t SP = (size_t)2048 * LD_H1;
    const float* pr = part + (size_t)row * LD_H1;
    short* o = h1 + (size_t)row * LD_H1;
#pragma unroll
    for (int u = 0; u < 3; u++) {
        int c = tid + u * 256;
        float s = b[c];
#pragma unroll
        for (int z = 0; z < 4; z++) s += pr[z * SP + c];
        o[c] = f2bf(s);
    }
    if (tid < 3) {
        int c = 768 + tid;
        float s = b[c];
#pragma unroll
        for (int z = 0; z < 4; z++) s += pr[z * SP + c];
        o[c] = f2bf(s);
    }
}

// fc2 partials (8, bf16) + bias + residual x2 -> out fp32
__global__ __launch_bounds__(256) void reduce_fc2(
        const short* __restrict__ part, const float* __restrict__ b,
        const float* __restrict__ x2, float* __restrict__ out) {
    int t = blockIdx.x * 256 + threadIdx.x;     // 4-elem group; 393216 total
    int row = t / 192;
    int c = (t - row * 192) * 4;
    size_t off = (size_t)row * 768 + c;
    const size_t SP = (size_t)2048 * 768;
    float4 bb = *(const float4*)(b + c);
    float4 xx = *(const float4*)(x2 + off);
    float o0 = bb.x + xx.x, o1 = bb.y + xx.y, o2 = bb.z + xx.z, o3 = bb.w + xx.w;
#pragma unroll
    for (int z = 0; z < 8; z++) {
        short4 v = *(const short4*)(part + z * SP + off);
        o0 += bf2f(v.x); o1 += bf2f(v.y); o2 += bf2f(v.z); o3 += bf2f(v.w);
    }
    float4 o = make_float4(o0, o1, o2, o3);
    *(float4*)(out + off) = o;
}

// ---------------- expand h1 [2048][772] -> Avqc [8192][768] (bf16) ---------

__global__ __launch_bounds__(256) void expand_kernel(const short* __restrict__ h1,
                                                     short* __restrict__ out) {
    int t = blockIdx.x * 256 + threadIdx.x;
    int r = t / 192;
    int c4 = (t - r * 192) * 4;
    const short* s = h1 + (size_t)(r >> 2) * LD_H1 + (r & 3) + c4;
    short4 v = make_short4(s[0], s[1], s[2], s[3]);
    *(short4*)(out + (size_t)r * M_DIM + c4) = v;
}

// ---------------- MFMA fused attention (single-buffer, R4-proven) ----------

__global__ __launch_bounds__(256) void attn_mfma(
        const short* __restrict__ Qb,    // [2048][768] bf16
        const short* __restrict__ Kf,    // frag-major
        const short* __restrict__ Vf,    // frag-major
        const float* __restrict__ kn,    // [24][1024]
        const float* __restrict__ pond,
        short* __restrict__ vals) {      // [2048][768] bf16
    __shared__ __align__(16) short Kt[4096];
    __shared__ __align__(16) short Vt[4096];
    __shared__ float knl[1024];
    __shared__ float qn_l[4][16];
    __shared__ float is_l[4][16];
    __shared__ __align__(16) short Pe[4 * 16 * 72];
    __shared__ __align__(16) short Pr[4 * 16 * 72];

    const int tid = threadIdx.x;
    const int lane = tid & 63;
    const int wave = tid >> 6;
    const int ml = lane & 15;
    const int kq = lane >> 4;
    const int qt = blockIdx.x, h = blockIdx.y, b = blockIdx.z;
    const int bh = b * H_CNT + h;

    for (int i = tid; i < 1024; i += 256) knl[i] = kn[bh * 1024 + i];

    const int qrow = b * S_LEN + qt * 64 + wave * 16 + ml;
    const short* qp = Qb + (size_t)qrow * 768 + h * 64 + kq * 8;
    bf16x8 aq0 = *(const bf16x8*)qp;
    bf16x8 aq1 = *(const bf16x8*)(qp + 32);

    float qn_part = 0.f;
#pragma unroll
    for (int e = 0; e < 8; e++) {
        float v0 = bf2f(aq0[e]), v1 = bf2f(aq1[e]);
        qn_part += v0 * v0 + v1 * v1;
    }
    qn_part += __shfl_xor(qn_part, 16);
    qn_part += __shfl_xor(qn_part, 32);
    if (kq == 0) {
        qn_l[wave][ml] = qn_part;
        float sig = fminf(fmaxf(qn_part, 1e-8f), 1e4f);
        is_l[wave][ml] = 1.0f / sig;
    }
    __syncthreads();

    float qn_r[4], is_r[4];
#pragma unroll
    for (int r = 0; r < 4; r++) {
        qn_r[r] = qn_l[wave][kq * 4 + r];
        is_r[r] = is_l[wave][kq * 4 + r];
    }

    f32x4 Oe[4], Or[4];
#pragma unroll
    for (int dt = 0; dt < 4; dt++) { Oe[dt] = {0.f,0.f,0.f,0.f}; Or[dt] = {0.f,0.f,0.f,0.f}; }
    float es_p[4] = {0.f,0.f,0.f,0.f}, rs_p[4] = {0.f,0.f,0.f,0.f};

    const short* KfB = Kf + (size_t)bh * 65536;
    const short* VfB = Vf + (size_t)bh * 65536;
    short* PeW = Pe + wave * 1152;
    short* PrW = Pr + wave * 1152;

    for (int t = 0; t < 16; t++) {
        __syncthreads();
        {
            const short* sk = KfB + t * 4096 + tid * 8;
            gld_lds16(Kt + tid * 8, sk);
            gld_lds16(Kt + 2048 + tid * 8, sk + 2048);
            const short* sv = VfB + t * 4096 + tid * 8;
            gld_lds16(Vt + tid * 8, sv);
            gld_lds16(Vt + 2048 + tid * 8, sv + 2048);
        }
        __syncthreads();

#pragma unroll
        for (int jtl = 0; jtl < 4; jtl++) {
            bf16x8 bk0 = *(const bf16x8*)&Kt[(jtl * 2 + 0) * 512 + lane * 8];
            bf16x8 bk1 = *(const bf16x8*)&Kt[(jtl * 2 + 1) * 512 + lane * 8];
            f32x4 c = {0.f,0.f,0.f,0.f};
            c = __builtin_amdgcn_mfma_f32_16x16x32_bf16(aq0, bk0, c, 0, 0, 0);
            c = __builtin_amdgcn_mfma_f32_16x16x32_bf16(aq1, bk1, c, 0, 0, 0);
            float knj = knl[t * 64 + jtl * 16 + ml];
#pragma unroll
            for (int r = 0; r < 4; r++) {
                float qk = c[r];
                float e = __expf(qk * 0.125f);
                float tt = (2.f * qk - qn_r[r] - knj) * is_r[r];
                float rb = fminf(__expf(tt), 1.0f);
                es_p[r] += e; rs_p[r] += rb;
                PeW[(kq * 4 + r) * 72 + jtl * 16 + ml] = f2bf(e);
                PrW[(kq * 4 + r) * 72 + jtl * 16 + ml] = f2bf(rb);
            }
        }
        __syncthreads();

#pragma unroll
        for (int jcl = 0; jcl < 2; jcl++) {
            bf16x8 pa_e = *(const bf16x8*)&PeW[ml * 72 + jcl * 32 + kq * 8];
            bf16x8 pa_r = *(const bf16x8*)&PrW[ml * 72 + jcl * 32 + kq * 8];
#pragma unroll
            for (int dt = 0; dt < 4; dt++) {
                bf16x8 bv = *(const bf16x8*)&Vt[(jcl * 4 + dt) * 512 + lane * 8];
                Oe[dt] = __builtin_amdgcn_mfma_f32_16x16x32_bf16(pa_e, bv, Oe[dt], 0, 0, 0);
                Or[dt] = __builtin_amdgcn_mfma_f32_16x16x32_bf16(pa_r, bv, Or[dt], 0, 0, 0);
            }
        }
    }

#pragma unroll
    for (int off = 1; off <= 8; off <<= 1) {
#pragma unroll
        for (int r = 0; r < 4; r++) {
            es_p[r] += __shfl_xor(es_p[r], off);
            rs_p[r] += __shfl_xor(rs_p[r], off);
        }
    }

    float p = pond[0];
    float sv = 1.0f / (1.0f + __expf(-p));
    float p0 = 1.0f - sv, p1 = sv;
    float blendinv = 1.0f / (p0 + p1 + 1e-7f);
    float we[4], wr[4];
#pragma unroll
    for (int r = 0; r < 4; r++) {
        we[r] = p0 * blendinv / es_p[r];
        wr[r] = p1 * blendinv / fmaxf(rs_p[r], 1e-8f);
    }

#pragma unroll
    for (int dt = 0; dt < 4; dt++) {
#pragma unroll
        for (int r = 0; r < 4; r++) {
            float v = Oe[dt][r] * we[r] + Or[dt][r] * wr[r];
            int token = b * S_LEN + qt * 64 + wave * 16 + kq * 4 + r;
            vals[(size_t)token * 768 + h * 64 + dt * 16 + ml] = f2bf(v);
        }
    }
}

// ---------------- launcher -------------------------------------------------

extern "C" void kernel_launch(void* const* d_in, const int* in_sizes, int n_in,
                              void* d_out, int out_size, void* d_ws, size_t ws_size,
                              hipStream_t stream) {
    const float* x     = (const float*)d_in[0];
    const float* ln1_w = (const float*)d_in[1];
    const float* ln1_b = (const float*)d_in[2];
    const float* Wq    = (const float*)d_in[3];
    const float* bq    = (const float*)d_in[4];
    const float* Wk    = (const float*)d_in[5];
    const float* bk    = (const float*)d_in[6];
    const float* Wv    = (const float*)d_in[7];
    const float* bv    = (const float*)d_in[8];
    const float* Wo    = (const float*)d_in[9];
    const float* bo    = (const float*)d_in[10];
    const float* pond  = (const float*)d_in[11];
    const float* ln2_w = (const float*)d_in[12];
    const float* ln2_b = (const float*)d_in[13];
    const float* fc1_W = (const float*)d_in[14];
    const float* fc1_b = (const float*)d_in[15];
    const float* vqc_W = (const float*)d_in[16];
    const float* vqc_b = (const float*)d_in[17];
    const float* fc2_W = (const float*)d_in[18];
    const float* fc2_b = (const float*)d_in[19];
    float* out = (float*)d_out;

    char* p = (char*)d_ws;
    short* Qb   = (short*)p;  p += (size_t)2048 * 768 * 2;
    short* Kfb  = (short*)p;  p += (size_t)2048 * 768 * 2;
    short* Vfb  = (short*)p;  p += (size_t)2048 * 768 * 2;
    float* x2   = (float*)p;  p += (size_t)2048 * 768 * 4;
    float* kn   = (float*)p;  p += (size_t)24576 * 4;
    float* bqkv = (float*)p;  p += 2304 * 4;
    short* actb = (short*)p;  p += (size_t)2048 * 768 * 2;
    short* h1   = (short*)p;  p += (size_t)2048 * LD_H1 * 2;
    short* g    = (short*)p;  p += (size_t)2048 * 3072 * 2;
    short* Avqc = (short*)p;  p += (size_t)8192 * 768 * 2;
    float* partb = (float*)p; p += (size_t)4 * 2048 * LD_H1 * 4;   // split-K partials (25.3 MB)
    short* wreg = (short*)p;  p += (size_t)5900544 * 2;
    short* Wqkvb = wreg;
    short* Wob   = wreg + 1769472;
    short* fc1b  = wreg + 2359296;
    short* vqcb  = wreg + 2951424;
    short* fc2b  = wreg + 3541248;

    dim3 blk(256);
    const size_t SP768 = (size_t)2048 * 768;
    const size_t SP772 = (size_t)2048 * LD_H1;

    convert_weights<<<5763, blk, 0, stream>>>(Wq, Wk, Wv, Wo, fc1_W, vqc_W, fc2_W, wreg);
    concat_bias<<<9, blk, 0, stream>>>(bq, bk, bv, bqkv);

    // 1. ln1 -> actb (bf16)
    ln_kernel<<<2048, blk, 0, stream>>>(x, ln1_w, ln1_b, actb);
    // 2. fused QKV projection -> Qb row-major, Kf/Vf frag-major (all bf16)
    gemm_bf16<<<dim3(18, 16, 1), blk, 0, stream>>>(actb, 768, Wqkvb, 768, bqkv, nullptr, 0,
                                                   Qb, 768, 0, Kfb, Vfb, 2304, 768, 3, 0, 0);
    // 3. k norms from Kf
    knorm2<<<96, blk, 0, stream>>>(Kfb, kn);
    // 4. MFMA attention -> vals (actb, bf16)
    attn_mfma<<<dim3(16, 12, 2), blk, 0, stream>>>(Qb, Kfb, Vfb, kn, pond, actb);
    // 5. Wo split-K x4 -> fp32 partials
    gemm_bf16<<<dim3(6, 16, 4), blk, 0, stream>>>(actb, 768, Wob, 768, bo, nullptr, 0,
                                                  partb, 768, SP768, nullptr, nullptr,
                                                  768, 192, 4, 0, 0);
    // 6. reduce + bo + residual(x) -> x2 fp32, fused ln2 -> actb
    reduce_wo_ln<<<2048, blk, 0, stream>>>(partb, bo, x, ln2_w, ln2_b, x2, actb);
    // 7. fc1 split-K x4 (N=771) -> fp32 partials [2048][772]
    gemm_bf16<<<dim3(7, 16, 4), blk, 0, stream>>>(actb, 768, fc1b, 768, fc1_b, nullptr, 0,
                                                  partb, LD_H1, SP772, nullptr, nullptr,
                                                  N_FC1, 192, 4, 0, 0);
    // 8. reduce + bias -> h1 bf16
    reduce_fc1<<<2048, blk, 0, stream>>>(partb, fc1_b, h1);
    // 9. expand slices -> Avqc [8192][768]
    expand_kernel<<<6144, blk, 0, stream>>>(h1, Avqc);
    // 10. vqc + gelu + transpose scatter -> g bf16 [2048][3072]
    gemm_bf16<<<dim3(6, 64, 1), blk, 0, stream>>>(Avqc, 768, vqcb, 768, vqc_b, nullptr, 0,
                                                  g, 3072, 0, nullptr, nullptr, 768, 768, 2, 1, 0);
    // 11. fc2 split-K x8 -> bf16 partials (fits the same 25 MB buffer)
    gemm_bf16<<<dim3(6, 16, 8), blk, 0, stream>>>(g, 3072, fc2b, 3072, fc2_b, nullptr, 0,
                                                  partb, 768, SP768, nullptr, nullptr,
                                                  768, 384, 5, 0, 0);
    // 12. reduce + bias + residual(x2) -> out fp32
    reduce_fc2<<<1536, blk, 0, stream>>>((const short*)partb, fc2_b, x2, out);
}

// Round 7
// 288.819 us; speedup vs baseline: 2.4169x; 2.4135x over previous
//
#include <hip/hip_runtime.h>
#include <math.h>

#define E_DIM 768
#define S_LEN 1024
#define B_SZ 2
#define H_CNT 12
#define D_HEAD 64
#define M_DIM 768
#define Q_STRIDE 4
#define N_FC1 771            // only M+Q-1 columns of fc1 are consumed
#define LD_H1 772            // padded row stride for h1 (bf16 elements)

typedef __attribute__((ext_vector_type(8))) short bf16x8;
typedef __attribute__((ext_vector_type(4))) float f32x4;

#define AS1 __attribute__((address_space(1)))
#define AS3 __attribute__((address_space(3)))

__device__ __forceinline__ void gld_lds16(void* lds, const void* g) {
    __builtin_amdgcn_global_load_lds((const AS1 void*)g, (AS3 void*)lds, 16, 0, 0);
}

__device__ __forceinline__ short f2bf(float f) {
    unsigned u = __float_as_uint(f);
    unsigned r = (u + 0x7fffu + ((u >> 16) & 1u)) >> 16;
    return (short)r;
}

__device__ __forceinline__ float bf2f(short s) {
    return __uint_as_float(((unsigned)(unsigned short)s) << 16);
}

// ---------------- block reduction helper (256 threads, 4 waves) ------------

__device__ __forceinline__ float block_reduce_sum(float v, volatile float* red) {
#pragma unroll
    for (int off = 32; off > 0; off >>= 1) v += __shfl_xor(v, off);
    __syncthreads();
    if ((threadIdx.x & 63) == 0) red[threadIdx.x >> 6] = v;
    __syncthreads();
    return red[0] + red[1] + red[2] + red[3];
}

// ---------------- weight fp32 -> bf16 conversion ---------------------------

__global__ __launch_bounds__(256) void convert_weights(
        const float* __restrict__ Wq, const float* __restrict__ Wk,
        const float* __restrict__ Wv, const float* __restrict__ Wo,
        const float* __restrict__ fc1W, const float* __restrict__ vqcW,
        const float* __restrict__ fc2W, short* __restrict__ dst) {
    int t = blockIdx.x * 256 + threadIdx.x;       // float4 index
    if (t >= 1475136) return;                     // 5900544 / 4
    int e = t * 4;
    const float* src; int off;
    if      (e < 589824)  { src = Wq;   off = e; }
    else if (e < 1179648) { src = Wk;   off = e - 589824; }
    else if (e < 1769472) { src = Wv;   off = e - 1179648; }
    else if (e < 2359296) { src = Wo;   off = e - 1769472; }
    else if (e < 2951424) { src = fc1W; off = e - 2359296; }
    else if (e < 3541248) { src = vqcW; off = e - 2951424; }
    else                  { src = fc2W; off = e - 3541248; }
    float4 v = *(const float4*)(src + off);
    short4 o = make_short4(f2bf(v.x), f2bf(v.y), f2bf(v.z), f2bf(v.w));
    *(short4*)(dst + e) = o;
}

__global__ void concat_bias(const float* __restrict__ bq, const float* __restrict__ bk,
                            const float* __restrict__ bv, float* __restrict__ bqkv) {
    int i = blockIdx.x * 256 + threadIdx.x;
    if (i >= 2304) return;
    float v = (i < 768) ? bq[i] : (i < 1536) ? bk[i - 768] : bv[i - 1536];
    bqkv[i] = v;
}

// ---------------- LayerNorm: one block per row, E=768, bf16 out ------------

__global__ __launch_bounds__(256) void ln_kernel(const float* __restrict__ x,
                                                 const float* __restrict__ w,
                                                 const float* __restrict__ b,
                                                 short* __restrict__ out) {
    __shared__ float red[4];
    int row = blockIdx.x;
    int tid = threadIdx.x;
    const float* xr = x + (size_t)row * E_DIM;
    float v0 = xr[tid], v1 = xr[tid + 256], v2 = xr[tid + 512];
    float s = block_reduce_sum(v0 + v1 + v2, red);
    float mu = s * (1.0f / E_DIM);
    float d0 = v0 - mu, d1 = v1 - mu, d2 = v2 - mu;
    float var = block_reduce_sum(d0 * d0 + d1 * d1 + d2 * d2, red) * (1.0f / E_DIM);
    float rs = rsqrtf(var + 1e-5f);
    short* orow = out + (size_t)row * E_DIM;
    orow[tid]       = f2bf(d0 * rs * w[tid]       + b[tid]);
    orow[tid + 256] = f2bf(d1 * rs * w[tid + 256] + b[tid + 256]);
    orow[tid + 512] = f2bf(d2 * rs * w[tid + 512] + b[tid + 512]);
}

// ---------------- k row norms from frag-major Kf ---------------------------

__global__ __launch_bounds__(256) void knorm2(const short* __restrict__ Kf,
                                              float* __restrict__ kn) {
    int idx = blockIdx.x * 256 + threadIdx.x;   // bh*1024 + s
    int s = idx & 1023, bh = idx >> 10;
    int jt = s >> 4, ml = s & 15;
    const short* base = Kf + (size_t)(bh * 64 + jt) * 1024 + ml * 8;
    float sum = 0.f;
#pragma unroll
    for (int c = 0; c < 2; c++)
#pragma unroll
        for (int kq = 0; kq < 4; kq++) {
            const short* p = base + c * 512 + kq * 128;
#pragma unroll
            for (int e = 0; e < 8; e++) { float v = bf2f(p[e]); sum += v * v; }
        }
    kn[idx] = sum;
}

// ---------------- bf16 MFMA NT GEMM (single-buffer, templated epilogue) ----
// 128x128 tile, BK=32, 256 threads (4 waves 2x2), global_load_lds width 16.
// LDS k-slot XOR swizzle (slot = k ^ ((m>>1)&3)) -> 2-way bank aliasing (free).
// Split-K via blockIdx.z: block covers K range [z*klen, (z+1)*klen).
// OUTMODE is a template param: the R5/R6 runtime-branch epilogue flipped the
// register allocator into a 68-VGPR spill regime (WRITE_SIZE 9MB->440MB).
// Each instantiation has a dead-branch-free epilogue; __launch_bounds__(256,2)
// pins the budget at <=256 VGPR so the allocator never targets 8 waves/SIMD.
// OUTMODE: 2 bf16 transpose-scatter (vqc); 3 QKV split (Q row-major,
//          K/V frag-major); 4 fp32 partial at outp + z*spitch;
//          5 bf16 partial at outp + z*spitch.

template <int OUTMODE>
__global__ __launch_bounds__(256, 2) void gemm_bf16(
        const short* __restrict__ A, int lda,
        const short* __restrict__ W, int ldw,
        const float* __restrict__ bias,
        void* __restrict__ outp, int ldo, size_t spitch,
        short* __restrict__ Kfp, short* __restrict__ Vfp,
        int N, int klen, int dogelu) {
    __shared__ short At[128 * 32];
    __shared__ short Bt[128 * 32];
    const int tid = threadIdx.x;
    const int lane = tid & 63;
    const int wave = tid >> 6;
    const int wr = (wave >> 1) * 64;
    const int wc = (wave & 1) * 64;
    const int ml = lane & 15;
    const int kq = lane >> 4;
    const int row0 = blockIdx.y * 128;
    const int col0 = blockIdx.x * 128;
    const int kbase = blockIdx.z * klen;

    // staging: chunk c -> LDS shorts [c*8, c*8+8); logical (m=c>>2,
    // kslot=c&3); source k-chunk = kslot ^ ((m>>1)&3)  (XOR swizzle)
    const int c0 = tid, c1 = tid + 256;
    const int am0 = c0 >> 2, ak0 = (((c0 & 3) ^ ((am0 >> 1) & 3))) * 8;
    const int am1 = c1 >> 2, ak1 = (((c1 & 3) ^ ((am1 >> 1) & 3))) * 8;
    const short* Ag0 = A + (size_t)(row0 + am0) * lda + ak0 + kbase;
    const short* Ag1 = A + (size_t)(row0 + am1) * lda + ak1 + kbase;
    int wrow0 = col0 + am0; if (wrow0 > N - 1) wrow0 = N - 1;
    int wrow1 = col0 + am1; if (wrow1 > N - 1) wrow1 = N - 1;
    const short* Wg0 = W + (size_t)wrow0 * ldw + ak0 + kbase;
    const short* Wg1 = W + (size_t)wrow1 * ldw + ak1 + kbase;

    const int kxor = (kq ^ ((ml >> 1) & 3)) * 8;   // reader swizzle

    f32x4 zero = {0.f, 0.f, 0.f, 0.f};
    f32x4 acc[4][4];
#pragma unroll
    for (int i = 0; i < 4; i++)
#pragma unroll
        for (int j = 0; j < 4; j++) acc[i][j] = zero;

    for (int k0 = 0; k0 < klen; k0 += 32) {
        gld_lds16(At + c0 * 8, Ag0 + k0);
        gld_lds16(At + c1 * 8, Ag1 + k0);
        gld_lds16(Bt + c0 * 8, Wg0 + k0);
        gld_lds16(Bt + c1 * 8, Wg1 + k0);
        __syncthreads();
        bf16x8 af[4], bfr[4];
#pragma unroll
        for (int i = 0; i < 4; i++)
            af[i] = *(const bf16x8*)&At[(wr + i * 16 + ml) * 32 + kxor];
#pragma unroll
        for (int j = 0; j < 4; j++)
            bfr[j] = *(const bf16x8*)&Bt[(wc + j * 16 + ml) * 32 + kxor];
#pragma unroll
        for (int i = 0; i < 4; i++)
#pragma unroll
            for (int j = 0; j < 4; j++)
                acc[i][j] = __builtin_amdgcn_mfma_f32_16x16x32_bf16(af[i], bfr[j], acc[i][j], 0, 0, 0);
        __syncthreads();
    }

    // epilogue: C/D layout col = lane&15, row = (lane>>4)*4 + reg
#pragma unroll
    for (int i = 0; i < 4; i++) {
#pragma unroll
        for (int j = 0; j < 4; j++) {
#pragma unroll
            for (int rr = 0; rr < 4; rr++) {
                int r = row0 + wr + i * 16 + kq * 4 + rr;
                int c = col0 + wc + j * 16 + ml;
                if (c < N) {
                    float v = acc[i][j][rr];
                    if (OUTMODE < 4) v += bias[c];
                    if (OUTMODE == 2 && dogelu)
                        v = 0.5f * v * (1.0f + erff(v * 0.70710678118654752f));
                    if (OUTMODE == 2) {
                        ((short*)outp)[(size_t)(r >> 2) * ldo + c * 4 + (r & 3)] = f2bf(v);
                    } else if (OUTMODE == 4) {
                        ((float*)outp)[blockIdx.z * spitch + (size_t)r * ldo + c] = v;
                    } else if (OUTMODE == 5) {
                        ((short*)outp)[blockIdx.z * spitch + (size_t)r * ldo + c] = f2bf(v);
                    } else if (OUTMODE == 3) {
                        int s = r & 1023, bb = r >> 10;
                        if (c < 768) {
                            ((short*)outp)[(size_t)r * 768 + c] = f2bf(v);
                        } else if (c < 1536) {
                            int df = c - 768; int hh = df >> 6, d = df & 63;
                            int bh2 = bb * 12 + hh;
                            size_t idx = ((size_t)(bh2 * 64 + (s >> 4)) * 2 + (d >> 5)) * 512
                                       + (size_t)((d >> 3) & 3) * 128 + (size_t)(s & 15) * 8 + (d & 7);
                            Kfp[idx] = f2bf(v);
                        } else {
                            int df = c - 1536; int hh = df >> 6, d = df & 63;
                            int bh2 = bb * 12 + hh;
                            size_t idx = ((size_t)(bh2 * 32 + (s >> 5))) * 2048
                                       + (size_t)(d >> 4) * 512 + (size_t)((s >> 3) & 3) * 128
                                       + (size_t)(d & 15) * 8 + (s & 7);
                            Vfp[idx] = f2bf(v);
                        }
                    }
                }
            }
        }
    }
}

// ---------------- split-K reduce kernels -----------------------------------

// Wo partials (4, fp32) + bo + residual x -> x2 fp32, then LN(ln2) -> y bf16
__global__ __launch_bounds__(256) void reduce_wo_ln(
        const float* __restrict__ part, const float* __restrict__ bo,
        const float* __restrict__ x, const float* __restrict__ w,
        const float* __restrict__ bvec, float* __restrict__ x2,
        short* __restrict__ y) {
    __shared__ float red[4];
    int row = blockIdx.x, tid = threadIdx.x;
    const size_t SP = (size_t)2048 * 768;
    const float* pr = part + (size_t)row * 768;
    const float* xr = x + (size_t)row * 768;
    float* x2r = x2 + (size_t)row * 768;
    float v[3];
#pragma unroll
    for (int u = 0; u < 3; u++) {
        int c = tid + u * 256;
        float s = bo[c] + xr[c];
#pragma unroll
        for (int z = 0; z < 4; z++) s += pr[z * SP + c];
        v[u] = s; x2r[c] = s;
    }
    float s = block_reduce_sum(v[0] + v[1] + v[2], red);
    float mu = s * (1.0f / 768.f);
    float d0 = v[0] - mu, d1 = v[1] - mu, d2 = v[2] - mu;
    float var = block_reduce_sum(d0 * d0 + d1 * d1 + d2 * d2, red) * (1.0f / 768.f);
    float rs = rsqrtf(var + 1e-5f);
    short* orow = y + (size_t)row * 768;
    orow[tid]       = f2bf(d0 * rs * w[tid]       + bvec[tid]);
    orow[tid + 256] = f2bf(d1 * rs * w[tid + 256] + bvec[tid + 256]);
    orow[tid + 512] = f2bf(d2 * rs * w[tid + 512] + bvec[tid + 512]);
}

// fc1 partials (4, fp32) + bias -> h1 bf16 [2048][772], cols 0..770
__global__ __launch_bounds__(256) void reduce_fc1(
        const float* __restrict__ part, const float* __restrict__ b,
        short* __restrict__ h1) {
    int row = blockIdx.x, tid = threadIdx.x;
    const size_t SP = (size_t)2048 * LD_H1;
    const float* pr = part + (size_t)row * LD_H1;
    short* o = h1 + (size_t)row * LD_H1;
#pragma unroll
    for (int u = 0; u < 3; u++) {
        int c = tid + u * 256;
        float s = b[c];
#pragma unroll
        for (int z = 0; z < 4; z++) s += pr[z * SP + c];
        o[c] = f2bf(s);
    }
    if (tid < 3) {
        int c = 768 + tid;
        float s = b[c];
#pragma unroll
        for (int z = 0; z < 4; z++) s += pr[z * SP + c];
        o[c] = f2bf(s);
    }
}

// fc2 partials (8, bf16) + bias + residual x2 -> out fp32
__global__ __launch_bounds__(256) void reduce_fc2(
        const short* __restrict__ part, const float* __restrict__ b,
        const float* __restrict__ x2, float* __restrict__ out) {
    int t = blockIdx.x * 256 + threadIdx.x;     // 4-elem group; 393216 total
    int row = t / 192;
    int c = (t - row * 192) * 4;
    size_t off = (size_t)row * 768 + c;
    const size_t SP = (size_t)2048 * 768;
    float4 bb = *(const float4*)(b + c);
    float4 xx = *(const float4*)(x2 + off);
    float o0 = bb.x + xx.x, o1 = bb.y + xx.y, o2 = bb.z + xx.z, o3 = bb.w + xx.w;
#pragma unroll
    for (int z = 0; z < 8; z++) {
        short4 v = *(const short4*)(part + z * SP + off);
        o0 += bf2f(v.x); o1 += bf2f(v.y); o2 += bf2f(v.z); o3 += bf2f(v.w);
    }
    float4 o = make_float4(o0, o1, o2, o3);
    *(float4*)(out + off) = o;
}

// ---------------- expand h1 [2048][772] -> Avqc [8192][768] (bf16) ---------

__global__ __launch_bounds__(256) void expand_kernel(const short* __restrict__ h1,
                                                     short* __restrict__ out) {
    int t = blockIdx.x * 256 + threadIdx.x;
    int r = t / 192;
    int c4 = (t - r * 192) * 4;
    const short* s = h1 + (size_t)(r >> 2) * LD_H1 + (r & 3) + c4;
    short4 v = make_short4(s[0], s[1], s[2], s[3]);
    *(short4*)(out + (size_t)r * M_DIM + c4) = v;
}

// ---------------- MFMA fused attention (single-buffer, R4-proven) ----------

__global__ __launch_bounds__(256) void attn_mfma(
        const short* __restrict__ Qb,    // [2048][768] bf16
        const short* __restrict__ Kf,    // frag-major
        const short* __restrict__ Vf,    // frag-major
        const float* __restrict__ kn,    // [24][1024]
        const float* __restrict__ pond,
        short* __restrict__ vals) {      // [2048][768] bf16
    __shared__ __align__(16) short Kt[4096];
    __shared__ __align__(16) short Vt[4096];
    __shared__ float knl[1024];
    __shared__ float qn_l[4][16];
    __shared__ float is_l[4][16];
    __shared__ __align__(16) short Pe[4 * 16 * 72];
    __shared__ __align__(16) short Pr[4 * 16 * 72];

    const int tid = threadIdx.x;
    const int lane = tid & 63;
    const int wave = tid >> 6;
    const int ml = lane & 15;
    const int kq = lane >> 4;
    const int qt = blockIdx.x, h = blockIdx.y, b = blockIdx.z;
    const int bh = b * H_CNT + h;

    for (int i = tid; i < 1024; i += 256) knl[i] = kn[bh * 1024 + i];

    const int qrow = b * S_LEN + qt * 64 + wave * 16 + ml;
    const short* qp = Qb + (size_t)qrow * 768 + h * 64 + kq * 8;
    bf16x8 aq0 = *(const bf16x8*)qp;
    bf16x8 aq1 = *(const bf16x8*)(qp + 32);

    float qn_part = 0.f;
#pragma unroll
    for (int e = 0; e < 8; e++) {
        float v0 = bf2f(aq0[e]), v1 = bf2f(aq1[e]);
        qn_part += v0 * v0 + v1 * v1;
    }
    qn_part += __shfl_xor(qn_part, 16);
    qn_part += __shfl_xor(qn_part, 32);
    if (kq == 0) {
        qn_l[wave][ml] = qn_part;
        float sig = fminf(fmaxf(qn_part, 1e-8f), 1e4f);
        is_l[wave][ml] = 1.0f / sig;
    }
    __syncthreads();

    float qn_r[4], is_r[4];
#pragma unroll
    for (int r = 0; r < 4; r++) {
        qn_r[r] = qn_l[wave][kq * 4 + r];
        is_r[r] = is_l[wave][kq * 4 + r];
    }

    f32x4 Oe[4], Or[4];
#pragma unroll
    for (int dt = 0; dt < 4; dt++) { Oe[dt] = {0.f,0.f,0.f,0.f}; Or[dt] = {0.f,0.f,0.f,0.f}; }
    float es_p[4] = {0.f,0.f,0.f,0.f}, rs_p[4] = {0.f,0.f,0.f,0.f};

    const short* KfB = Kf + (size_t)bh * 65536;
    const short* VfB = Vf + (size_t)bh * 65536;
    short* PeW = Pe + wave * 1152;
    short* PrW = Pr + wave * 1152;

    for (int t = 0; t < 16; t++) {
        __syncthreads();
        {
            const short* sk = KfB + t * 4096 + tid * 8;
            gld_lds16(Kt + tid * 8, sk);
            gld_lds16(Kt + 2048 + tid * 8, sk + 2048);
            const short* sv = VfB + t * 4096 + tid * 8;
            gld_lds16(Vt + tid * 8, sv);
            gld_lds16(Vt + 2048 + tid * 8, sv + 2048);
        }
        __syncthreads();

#pragma unroll
        for (int jtl = 0; jtl < 4; jtl++) {
            bf16x8 bk0 = *(const bf16x8*)&Kt[(jtl * 2 + 0) * 512 + lane * 8];
            bf16x8 bk1 = *(const bf16x8*)&Kt[(jtl * 2 + 1) * 512 + lane * 8];
            f32x4 c = {0.f,0.f,0.f,0.f};
            c = __builtin_amdgcn_mfma_f32_16x16x32_bf16(aq0, bk0, c, 0, 0, 0);
            c = __builtin_amdgcn_mfma_f32_16x16x32_bf16(aq1, bk1, c, 0, 0, 0);
            float knj = knl[t * 64 + jtl * 16 + ml];
#pragma unroll
            for (int r = 0; r < 4; r++) {
                float qk = c[r];
                float e = __expf(qk * 0.125f);
                float tt = (2.f * qk - qn_r[r] - knj) * is_r[r];
                float rb = fminf(__expf(tt), 1.0f);
                es_p[r] += e; rs_p[r] += rb;
                PeW[(kq * 4 + r) * 72 + jtl * 16 + ml] = f2bf(e);
                PrW[(kq * 4 + r) * 72 + jtl * 16 + ml] = f2bf(rb);
            }
        }
        __syncthreads();

#pragma unroll
        for (int jcl = 0; jcl < 2; jcl++) {
            bf16x8 pa_e = *(const bf16x8*)&PeW[ml * 72 + jcl * 32 + kq * 8];
            bf16x8 pa_r = *(const bf16x8*)&PrW[ml * 72 + jcl * 32 + kq * 8];
#pragma unroll
            for (int dt = 0; dt < 4; dt++) {
                bf16x8 bv = *(const bf16x8*)&Vt[(jcl * 4 + dt) * 512 + lane * 8];
                Oe[dt] = __builtin_amdgcn_mfma_f32_16x16x32_bf16(pa_e, bv, Oe[dt], 0, 0, 0);
                Or[dt] = __builtin_amdgcn_mfma_f32_16x16x32_bf16(pa_r, bv, Or[dt], 0, 0, 0);
            }
        }
    }

#pragma unroll
    for (int off = 1; off <= 8; off <<= 1) {
#pragma unroll
        for (int r = 0; r < 4; r++) {
            es_p[r] += __shfl_xor(es_p[r], off);
            rs_p[r] += __shfl_xor(rs_p[r], off);
        }
    }

    float p = pond[0];
    float sv = 1.0f / (1.0f + __expf(-p));
    float p0 = 1.0f - sv, p1 = sv;
    float blendinv = 1.0f / (p0 + p1 + 1e-7f);
    float we[4], wr[4];
#pragma unroll
    for (int r = 0; r < 4; r++) {
        we[r] = p0 * blendinv / es_p[r];
        wr[r] = p1 * blendinv / fmaxf(rs_p[r], 1e-8f);
    }

#pragma unroll
    for (int dt = 0; dt < 4; dt++) {
#pragma unroll
        for (int r = 0; r < 4; r++) {
            float v = Oe[dt][r] * we[r] + Or[dt][r] * wr[r];
            int token = b * S_LEN + qt * 64 + wave * 16 + kq * 4 + r;
            vals[(size_t)token * 768 + h * 64 + dt * 16 + ml] = f2bf(v);
        }
    }
}

// ---------------- launcher -------------------------------------------------

extern "C" void kernel_launch(void* const* d_in, const int* in_sizes, int n_in,
                              void* d_out, int out_size, void* d_ws, size_t ws_size,
                              hipStream_t stream) {
    const float* x     = (const float*)d_in[0];
    const float* ln1_w = (const float*)d_in[1];
    const float* ln1_b = (const float*)d_in[2];
    const float* Wq    = (const float*)d_in[3];
    const float* bq    = (const float*)d_in[4];
    const float* Wk    = (const float*)d_in[5];
    const float* bk    = (const float*)d_in[6];
    const float* Wv    = (const float*)d_in[7];
    const float* bv    = (const float*)d_in[8];
    const float* Wo    = (const float*)d_in[9];
    const float* bo    = (const float*)d_in[10];
    const float* pond  = (const float*)d_in[11];
    const float* ln2_w = (const float*)d_in[12];
    const float* ln2_b = (const float*)d_in[13];
    const float* fc1_W = (const float*)d_in[14];
    const float* fc1_b = (const float*)d_in[15];
    const float* vqc_W = (const float*)d_in[16];
    const float* vqc_b = (const float*)d_in[17];
    const float* fc2_W = (const float*)d_in[18];
    const float* fc2_b = (const float*)d_in[19];
    float* out = (float*)d_out;

    char* p = (char*)d_ws;
    short* Qb   = (short*)p;  p += (size_t)2048 * 768 * 2;
    short* Kfb  = (short*)p;  p += (size_t)2048 * 768 * 2;
    short* Vfb  = (short*)p;  p += (size_t)2048 * 768 * 2;
    float* x2   = (float*)p;  p += (size_t)2048 * 768 * 4;
    float* kn   = (float*)p;  p += (size_t)24576 * 4;
    float* bqkv = (float*)p;  p += 2304 * 4;
    short* actb = (short*)p;  p += (size_t)2048 * 768 * 2;
    short* h1   = (short*)p;  p += (size_t)2048 * LD_H1 * 2;
    short* g    = (short*)p;  p += (size_t)2048 * 3072 * 2;
    short* Avqc = (short*)p;  p += (size_t)8192 * 768 * 2;
    float* partb = (float*)p; p += (size_t)4 * 2048 * LD_H1 * 4;   // split-K partials (25.3 MB)
    short* wreg = (short*)p;  p += (size_t)5900544 * 2;
    short* Wqkvb = wreg;
    short* Wob   = wreg + 1769472;
    short* fc1b  = wreg + 2359296;
    short* vqcb  = wreg + 2951424;
    short* fc2b  = wreg + 3541248;

    dim3 blk(256);
    const size_t SP768 = (size_t)2048 * 768;
    const size_t SP772 = (size_t)2048 * LD_H1;

    convert_weights<<<5763, blk, 0, stream>>>(Wq, Wk, Wv, Wo, fc1_W, vqc_W, fc2_W, wreg);
    concat_bias<<<9, blk, 0, stream>>>(bq, bk, bv, bqkv);

    // 1. ln1 -> actb (bf16)
    ln_kernel<<<2048, blk, 0, stream>>>(x, ln1_w, ln1_b, actb);
    // 2. fused QKV projection -> Qb row-major, Kf/Vf frag-major (all bf16)
    gemm_bf16<3><<<dim3(18, 16, 1), blk, 0, stream>>>(actb, 768, Wqkvb, 768, bqkv,
                                                      Qb, 768, 0, Kfb, Vfb, 2304, 768, 0);
    // 3. k norms from Kf
    knorm2<<<96, blk, 0, stream>>>(Kfb, kn);
    // 4. MFMA attention -> vals (actb, bf16)
    attn_mfma<<<dim3(16, 12, 2), blk, 0, stream>>>(Qb, Kfb, Vfb, kn, pond, actb);
    // 5. Wo split-K x4 -> fp32 partials
    gemm_bf16<4><<<dim3(6, 16, 4), blk, 0, stream>>>(actb, 768, Wob, 768, nullptr,
                                                     partb, 768, SP768, nullptr, nullptr,
                                                     768, 192, 0);
    // 6. reduce + bo + residual(x) -> x2 fp32, fused ln2 -> actb
    reduce_wo_ln<<<2048, blk, 0, stream>>>(partb, bo, x, ln2_w, ln2_b, x2, actb);
    // 7. fc1 split-K x4 (N=771) -> fp32 partials [2048][772]
    gemm_bf16<4><<<dim3(7, 16, 4), blk, 0, stream>>>(actb, 768, fc1b, 768, nullptr,
                                                     partb, LD_H1, SP772, nullptr, nullptr,
                                                     N_FC1, 192, 0);
    // 8. reduce + bias -> h1 bf16
    reduce_fc1<<<2048, blk, 0, stream>>>(partb, fc1_b, h1);
    // 9. expand slices -> Avqc [8192][768]
    expand_kernel<<<6144, blk, 0, stream>>>(h1, Avqc);
    // 10. vqc + gelu + transpose scatter -> g bf16 [2048][3072]
    gemm_bf16<2><<<dim3(6, 64, 1), blk, 0, stream>>>(Avqc, 768, vqcb, 768, vqc_b,
                                                     g, 3072, 0, nullptr, nullptr, 768, 768, 1);
    // 11. fc2 split-K x8 -> bf16 partials (fits the same 25 MB buffer)
    gemm_bf16<5><<<dim3(6, 16, 8), blk, 0, stream>>>(g, 3072, fc2b, 3072, nullptr,
                                                     partb, 768, SP768, nullptr, nullptr,
                                                     768, 384, 0);
    // 12. reduce + bias + residual(x2) -> out fp32
    reduce_fc2<<<1536, blk, 0, stream>>>((const short*)partb, fc2_b, x2, out);
}